// Round 4
// baseline (199.796 us; speedup 1.0000x reference)
//
#include <hip/hip_runtime.h>

constexpr int NG = 2048;   // gaussians
constexpr int DF = 64;     // feature dim
constexpr int IW = 128;
constexpr int IH = 128;
constexpr int SEG = 8;           // z-segments (waves per render block)
constexpr int SEGN = NG / SEG;   // 256 gaussians per segment
constexpr int RB = SEG * 64;     // 512 threads per render block

#define P_NEAR 0.01f
#define P_BLUR 0.3f
#define P_AMIN (1.0f/255.0f)
#define P_AMAX 0.999f

// render dynamic-LDS layout (floats) — 79,872 B => 2 blocks/CU (160 KiB LDS)
constexpr int L_LIST = 0;                       // SEG*SEGN ints = 2048
constexpr int L_T    = SEG * SEGN;              // 2048
constexpr int L_ACC  = L_T + SEG * 64;          // 2560
constexpr int ACC_STRIDE = 34;                  // 32 feats + 2 pad (8B-aligned rows)
constexpr int L_TOTAL = L_ACC + SEG * 64 * ACC_STRIDE;  // 19,968 floats = 79,872 B

// ---------------------------------------------------------------------------
__device__ inline void invert4x4(const float* m, float* inv) {
    inv[0]  =  m[5]*m[10]*m[15] - m[5]*m[11]*m[14] - m[9]*m[6]*m[15] + m[9]*m[7]*m[14] + m[13]*m[6]*m[11] - m[13]*m[7]*m[10];
    inv[4]  = -m[4]*m[10]*m[15] + m[4]*m[11]*m[14] + m[8]*m[6]*m[15] - m[8]*m[7]*m[14] - m[12]*m[6]*m[11] + m[12]*m[7]*m[10];
    inv[8]  =  m[4]*m[9]*m[15]  - m[4]*m[11]*m[13] - m[8]*m[5]*m[15] + m[8]*m[7]*m[13] + m[12]*m[5]*m[11] - m[12]*m[7]*m[9];
    inv[12] = -m[4]*m[9]*m[14]  + m[4]*m[10]*m[13] + m[8]*m[5]*m[14] - m[8]*m[6]*m[13] - m[12]*m[5]*m[10] + m[12]*m[6]*m[9];
    inv[1]  = -m[1]*m[10]*m[15] + m[1]*m[11]*m[14] + m[9]*m[2]*m[15] - m[9]*m[3]*m[14] - m[13]*m[2]*m[11] + m[13]*m[3]*m[10];
    inv[5]  =  m[0]*m[10]*m[15] - m[0]*m[11]*m[14] - m[8]*m[2]*m[15] + m[8]*m[3]*m[14] + m[12]*m[2]*m[11] - m[12]*m[3]*m[10];
    inv[9]  = -m[0]*m[9]*m[15]  + m[0]*m[11]*m[13] + m[8]*m[1]*m[15] - m[8]*m[3]*m[13] - m[12]*m[1]*m[11] + m[12]*m[3]*m[9];
    inv[13] =  m[0]*m[9]*m[14]  - m[0]*m[10]*m[13] - m[8]*m[1]*m[14] + m[8]*m[2]*m[13] + m[12]*m[1]*m[10] - m[12]*m[2]*m[9];
    inv[2]  =  m[1]*m[6]*m[15]  - m[1]*m[7]*m[14]  - m[5]*m[2]*m[15] + m[5]*m[3]*m[14] + m[13]*m[2]*m[7]  - m[13]*m[3]*m[6];
    inv[6]  = -m[0]*m[6]*m[15]  + m[0]*m[7]*m[14]  + m[4]*m[2]*m[15] - m[4]*m[3]*m[14] - m[12]*m[2]*m[7]  + m[12]*m[3]*m[6];
    inv[10] =  m[0]*m[5]*m[15]  - m[0]*m[7]*m[13]  - m[4]*m[1]*m[15] + m[4]*m[3]*m[13] + m[12]*m[1]*m[7]  - m[12]*m[3]*m[5];
    inv[14] = -m[0]*m[5]*m[14]  + m[0]*m[6]*m[13]  + m[4]*m[1]*m[14] - m[4]*m[2]*m[13] - m[12]*m[1]*m[6]  + m[12]*m[2]*m[5];
    inv[3]  = -m[1]*m[6]*m[11]  + m[1]*m[7]*m[10]  + m[5]*m[2]*m[11] - m[5]*m[3]*m[10] - m[9]*m[2]*m[7]   + m[9]*m[3]*m[6];
    inv[7]  =  m[0]*m[6]*m[11]  - m[0]*m[7]*m[10]  - m[4]*m[2]*m[11] + m[4]*m[3]*m[10] + m[8]*m[2]*m[7]   - m[8]*m[3]*m[6];
    inv[11] = -m[0]*m[5]*m[11]  + m[0]*m[7]*m[9]   + m[4]*m[1]*m[11] - m[4]*m[3]*m[9]  - m[8]*m[1]*m[7]   + m[8]*m[3]*m[5];
    inv[15] =  m[0]*m[5]*m[10]  - m[0]*m[6]*m[9]   - m[4]*m[1]*m[10] + m[4]*m[2]*m[9]  + m[8]*m[1]*m[6]   - m[8]*m[2]*m[5];
    float det = m[0]*inv[0] + m[1]*inv[4] + m[2]*inv[8] + m[3]*inv[12];
    det = 1.0f / det;
    #pragma unroll
    for (int i = 0; i < 16; ++i) inv[i] *= det;
}

// ---------------------------------------------------------------------------
// Kernel 1: per-gaussian projection (8 blocks x 256). Writes z-key + params.
__global__ __launch_bounds__(256) void preprocess_kernel(
    const float* __restrict__ means,  const float* __restrict__ quats,
    const float* __restrict__ scales, const float* __restrict__ opac_logits,
    const float* __restrict__ c2o,    const float* __restrict__ Kmat,
    float* __restrict__ zkey, float* __restrict__ evalp, float* __restrict__ bboxp)
{
    const int i = blockIdx.x * 256 + threadIdx.x;
    if (i >= NG) return;

    float inv[16];
    {
        float m[16];
        #pragma unroll
        for (int t = 0; t < 16; ++t) m[t] = c2o[t];
        invert4x4(m, inv);   // viewmat, row-major
    }
    const float fx = Kmat[0], fy = Kmat[4], cx = Kmat[2], cy = Kmat[5];

    float mx = means[i*3+0], my = means[i*3+1], mz = means[i*3+2];
    float X = inv[0]*mx + inv[1]*my + inv[2]*mz  + inv[3];
    float Y = inv[4]*mx + inv[5]*my + inv[6]*mz  + inv[7];
    float Z = inv[8]*mx + inv[9]*my + inv[10]*mz + inv[11];

    float qw = quats[i*4+0], qx = quats[i*4+1], qy = quats[i*4+2], qz = quats[i*4+3];
    float qn = rsqrtf(qw*qw + qx*qx + qy*qy + qz*qz);
    qw *= qn; qx *= qn; qy *= qn; qz *= qn;
    float R00 = 1.f - 2.f*(qy*qy + qz*qz), R01 = 2.f*(qx*qy - qw*qz), R02 = 2.f*(qx*qz + qw*qy);
    float R10 = 2.f*(qx*qy + qw*qz), R11 = 1.f - 2.f*(qx*qx + qz*qz), R12 = 2.f*(qy*qz - qw*qx);
    float R20 = 2.f*(qx*qz - qw*qy), R21 = 2.f*(qy*qz + qw*qx), R22 = 1.f - 2.f*(qx*qx + qy*qy);

    float s0 = expf(scales[i*3+0]), s1 = expf(scales[i*3+1]), s2 = expf(scales[i*3+2]);
    float M00 = R00*s0, M01 = R01*s1, M02 = R02*s2;
    float M10 = R10*s0, M11 = R11*s1, M12 = R12*s2;
    float M20 = R20*s0, M21 = R21*s1, M22 = R22*s2;

    float V[3][3];
    V[0][0] = M00*M00 + M01*M01 + M02*M02;
    V[0][1] = M00*M10 + M01*M11 + M02*M12;
    V[0][2] = M00*M20 + M01*M21 + M02*M22;
    V[1][1] = M10*M10 + M11*M11 + M12*M12;
    V[1][2] = M10*M20 + M11*M21 + M12*M22;
    V[2][2] = M20*M20 + M21*M21 + M22*M22;
    V[1][0] = V[0][1]; V[2][0] = V[0][2]; V[2][1] = V[1][2];

    float Rv[3][3] = {{inv[0],inv[1],inv[2]},{inv[4],inv[5],inv[6]},{inv[8],inv[9],inv[10]}};
    float Tm[3][3], C[3][3];
    #pragma unroll
    for (int r = 0; r < 3; ++r)
        #pragma unroll
        for (int c = 0; c < 3; ++c)
            Tm[r][c] = Rv[r][0]*V[0][c] + Rv[r][1]*V[1][c] + Rv[r][2]*V[2][c];
    #pragma unroll
    for (int r = 0; r < 3; ++r)
        #pragma unroll
        for (int c = 0; c < 3; ++c)
            C[r][c] = Tm[r][0]*Rv[c][0] + Tm[r][1]*Rv[c][1] + Tm[r][2]*Rv[c][2];

    float rz = 1.0f / Z;
    float j00 = fx*rz, j02 = -fx*X*rz*rz;
    float j11 = fy*rz, j12 = -fy*Y*rz*rz;

    float c00 = j00*j00*C[0][0] + 2.f*j00*j02*C[0][2] + j02*j02*C[2][2];
    float c01 = j00*j11*C[0][1] + j00*j12*C[0][2] + j02*j11*C[1][2] + j02*j12*C[2][2];
    float c11 = j11*j11*C[1][1] + 2.f*j11*j12*C[1][2] + j12*j12*C[2][2];

    float a = c00 + P_BLUR;
    float b = c01;
    float c = c11 + P_BLUR;
    float det = a*c - b*b;

    float pmx = fx*X*rz + cx;
    float pmy = fy*Y*rz + cy;

    float lam = 0.5f*(a + c) + sqrtf(fmaxf(0.25f*(a - c)*(a - c) + b*b, 1e-12f));
    float radius = 3.0f * sqrtf(lam);
    bool valid = (Z > P_NEAR) && (det > 0.0f) && (radius > 3.0f);

    float op = 1.0f / (1.0f + expf(-opac_logits[i]));

    float cA = 0.f, cB = 0.f, cC = 0.f, rx = -1e9f, ry = -1e9f;
    if (valid) {
        float rdet = 1.0f / det;
        cA = c * rdet; cB = -b * rdet; cC = a * rdet;
        // conservative extent: alpha >= A_MIN needs sigma <= ln(255*op);
        // min-over-dy sigma = dx^2/(2a) => |dx| <= sqrt(2*a*smax)
        float smax = logf(255.0f * op);
        if (smax > 0.f) {
            rx = sqrtf(2.f * a * smax) * 1.0001f + 1e-3f;
            ry = sqrtf(2.f * c * smax) * 1.0001f + 1e-3f;
        }
    } else {
        op = 0.f;
    }

    zkey[i] = Z;
    ((float4*)evalp)[i*2]   = make_float4(pmx, pmy, cA, cB);
    ((float4*)evalp)[i*2+1] = make_float4(cC, op, 0.f, 0.f);
    ((float4*)bboxp)[i]     = make_float4(pmx, pmy, rx, ry);
}

// ---------------------------------------------------------------------------
// Kernel 2: barrier-free stable rank sort + scatter. rank_i = #{j: z_j<z_i or
// (z_j==z_i and j<i)} — exactly jnp.argsort's stable order. Original index is
// stashed in evalps[8i+6] for the colors lookup.
__global__ __launch_bounds__(256) void rank_permute_kernel(
    const float* __restrict__ zkey, const float* __restrict__ evalp,
    const float* __restrict__ bboxp, float* __restrict__ evalps,
    float* __restrict__ bboxs)
{
    const int i = blockIdx.x * 256 + threadIdx.x;
    if (i >= NG) return;
    const float zi = zkey[i];
    const float4* z4 = (const float4*)zkey;
    int rank = 0;
    #pragma unroll 4
    for (int c = 0; c < NG/4; ++c) {
        float4 z = z4[c];
        int j = 4*c;
        rank += (z.x < zi) || (z.x == zi && (j+0) < i);
        rank += (z.y < zi) || (z.y == zi && (j+1) < i);
        rank += (z.z < zi) || (z.z == zi && (j+2) < i);
        rank += (z.w < zi) || (z.w == zi && (j+3) < i);
    }
    float4 lo = ((const float4*)evalp)[i*2];
    float4 hi = ((const float4*)evalp)[i*2+1];
    hi.z = __int_as_float(i);
    ((float4*)evalps)[rank*2]   = lo;
    ((float4*)evalps)[rank*2+1] = hi;
    ((float4*)bboxs)[rank]      = ((const float4*)bboxp)[i];
}

// ---------------------------------------------------------------------------
// Kernel 3: render. Grid = 256 tiles x 2 feature-halves. Block = 8 waves;
// wave s owns z-segment s, lane = pixel of the 8x8 tile, each wave
// accumulates 32 features (its block's half). ~100 VGPR + 78 KB LDS =>
// 2 blocks/CU = 4 waves/SIMD for latency hiding. Segment partials combined
// affinely in LDS: out = a0 + T0*(a1 + T1*(...)).
__global__ __launch_bounds__(RB, 4) void render_kernel(
    const float* __restrict__ evalps, const float* __restrict__ bboxs,
    const float* __restrict__ colors, float* __restrict__ out)
{
    extern __shared__ float lds[];
    const int tid  = threadIdx.x;
    const int lane = tid & 63;
    const int seg  = tid >> 6;
    const int bx   = blockIdx.x;
    const int tile = bx >> 1;
    const int fh   = bx & 1;               // feature half: 0 -> 0..31, 1 -> 32..63
    const int tx = (tile & 15) * 8;
    const int ty = (tile >> 4) * 8;
    const float px = tx + (lane & 7) + 0.5f;
    const float py = ty + (lane >> 3) + 0.5f;
    const float cxt = tx + 4.0f, cyt = ty + 4.0f;

    // ---- cull this z-segment into an LDS list (z order preserved)
    int* list = (int*)(lds + L_LIST) + seg * SEGN;
    int cnt = 0;
    const float4* bb4 = (const float4*)bboxs;
    for (int c = 0; c < SEGN; c += 64) {
        int g = seg * SEGN + c + lane;           // sorted position
        float4 bb = bb4[g];
        bool sel = (fabsf(bb.x - cxt) <= bb.z + 3.5f) &&
                   (fabsf(bb.y - cyt) <= bb.w + 3.5f);
        unsigned long long m = __ballot(sel);
        if (sel) list[cnt + (int)__popcll(m & ((1ull << lane) - 1ull))] = g;
        cnt += (int)__popcll(m);
    }

    float acc[32];
    #pragma unroll
    for (int f = 0; f < 32; ++f) acc[f] = 0.f;
    float T = 1.0f;

    const float4* ep4 = (const float4*)evalps;
    const float4* cp4 = (const float4*)colors + fh * 8;   // this half's columns

    for (int r = 0; r < cnt; ++r) {
        int g = list[r];
        float4 e0 = ep4[g*2], e1 = ep4[g*2+1];
        float dx = px - e0.x, dy = py - e0.y;
        float sig = 0.5f*(e0.z*dx*dx + e1.x*dy*dy) + e0.w*dx*dy;
        float al = fminf(e1.y * __expf(-sig), P_AMAX);
        al = (sig >= 0.f && al >= P_AMIN) ? al : 0.f;
        float wv = T * al;
        T *= (1.f - al);

        const float4* crow = cp4 + (size_t)(unsigned)__float_as_int(e1.z) * 16;
        #pragma unroll
        for (int q = 0; q < 8; ++q) {
            float4 cv = crow[q];                  // wave-uniform broadcast
            acc[4*q+0] = fmaf(wv, cv.x, acc[4*q+0]);
            acc[4*q+1] = fmaf(wv, cv.y, acc[4*q+1]);
            acc[4*q+2] = fmaf(wv, cv.z, acc[4*q+2]);
            acc[4*q+3] = fmaf(wv, cv.w, acc[4*q+3]);
        }
        if (__ballot(T >= 1e-6f) == 0) break;   // local-T residual < 1e-6: exact enough
    }

    // ---- stage per-segment (acc, T) to LDS
    {
        float* ab = lds + L_ACC + (size_t)(seg * 64 + lane) * ACC_STRIDE;
        #pragma unroll
        for (int q = 0; q < 16; ++q)
            *(float2*)(ab + 2*q) = make_float2(acc[2*q], acc[2*q+1]);
        lds[L_T + seg*64 + lane] = T;
    }
    __syncthreads();

    // ---- affine combine over segments + write out
    {
        int p  = tid >> 3;           // pixel in tile
        int fq = tid & 7;            // 4-feature group within the half
        float r0, r1, r2, r3;
        const float* ab = lds + L_ACC + (size_t)((SEG-1)*64 + p) * ACC_STRIDE + fq*4;
        { float2 u = *(const float2*)ab; float2 v = *(const float2*)(ab+2);
          r0 = u.x; r1 = u.y; r2 = v.x; r3 = v.y; }
        #pragma unroll
        for (int s = SEG - 2; s >= 0; --s) {
            float Ts = lds[L_T + s*64 + p];
            const float* as_ = lds + L_ACC + (size_t)(s*64 + p) * ACC_STRIDE + fq*4;
            float2 u = *(const float2*)as_; float2 v = *(const float2*)(as_+2);
            r0 = fmaf(Ts, r0, u.x); r1 = fmaf(Ts, r1, u.y);
            r2 = fmaf(Ts, r2, v.x); r3 = fmaf(Ts, r3, v.y);
        }
        int pyg = ty + (p >> 3), pxg = tx + (p & 7);
        float* op_ = out + (size_t)(pyg * IW + pxg) * DF + fh*32 + fq*4;
        *(float4*)op_ = make_float4(r0, r1, r2, r3);
    }
}

// ---------------------------------------------------------------------------
extern "C" void kernel_launch(void* const* d_in, const int* in_sizes, int n_in,
                              void* d_out, int out_size, void* d_ws, size_t ws_size,
                              hipStream_t stream) {
    const float* means  = (const float*)d_in[0];
    const float* quats  = (const float*)d_in[1];
    const float* scales = (const float*)d_in[2];
    const float* opac   = (const float*)d_in[3];
    const float* colors = (const float*)d_in[4];
    const float* c2o    = (const float*)d_in[5];
    const float* Kmat   = (const float*)d_in[6];
    float* out = (float*)d_out;

    // ws (floats): zkey[NG] | evalp[8NG] | bboxp[4NG] | evalps[8NG] | bboxs[4NG] = 200 KiB
    float* ws     = (float*)d_ws;
    float* zkey   = ws;
    float* evalp  = ws + NG;
    float* bboxp  = ws + NG*9;
    float* evalps = ws + NG*13;
    float* bboxs  = ws + NG*21;

    (void)hipFuncSetAttribute((const void*)render_kernel,
                              hipFuncAttributeMaxDynamicSharedMemorySize,
                              L_TOTAL * 4);

    preprocess_kernel<<<NG/256, 256, 0, stream>>>(means, quats, scales, opac, c2o, Kmat,
                                                  zkey, evalp, bboxp);
    rank_permute_kernel<<<NG/256, 256, 0, stream>>>(zkey, evalp, bboxp, evalps, bboxs);
    render_kernel<<<IH*IW/64 * 2, RB, L_TOTAL*4, stream>>>(evalps, bboxs, colors, out);
}

// Round 5
// 123.783 us; speedup vs baseline: 1.6141x; 1.6141x over previous
//
#include <hip/hip_runtime.h>

constexpr int NG = 2048;   // gaussians
constexpr int DF = 64;     // feature dim
constexpr int IW = 128;
constexpr int IH = 128;
constexpr int SEG = 8;           // z-segments (waves per render block)
constexpr int SEGN = NG / SEG;   // 256 gaussians per segment
constexpr int RB = SEG * 64;     // 512 threads per render block
constexpr int JC = 8;            // j-chunks for rank kernel
constexpr int JCN = NG / JC;     // 256 z's per chunk

#define P_NEAR 0.01f
#define P_BLUR 0.3f
#define P_AMIN (1.0f/255.0f)
#define P_AMAX 0.999f

// render dynamic-LDS layout (floats) — 145,408 B, 1 block/CU (measured 44.8us)
constexpr int L_LIST = 0;                       // SEG*SEGN ints = 2048
constexpr int L_T    = SEG * SEGN;              // 2048
constexpr int L_ACC  = L_T + SEG * 64;          // 2560
constexpr int ACC_STRIDE = 66;                  // 64 + 2 pad (8B-aligned rows)
constexpr int L_TOTAL = L_ACC + SEG * 64 * ACC_STRIDE;  // 36352 floats = 145408 B

// ---------------------------------------------------------------------------
__device__ inline void invert4x4(const float* m, float* inv) {
    inv[0]  =  m[5]*m[10]*m[15] - m[5]*m[11]*m[14] - m[9]*m[6]*m[15] + m[9]*m[7]*m[14] + m[13]*m[6]*m[11] - m[13]*m[7]*m[10];
    inv[4]  = -m[4]*m[10]*m[15] + m[4]*m[11]*m[14] + m[8]*m[6]*m[15] - m[8]*m[7]*m[14] - m[12]*m[6]*m[11] + m[12]*m[7]*m[10];
    inv[8]  =  m[4]*m[9]*m[15]  - m[4]*m[11]*m[13] - m[8]*m[5]*m[15] + m[8]*m[7]*m[13] + m[12]*m[5]*m[11] - m[12]*m[7]*m[9];
    inv[12] = -m[4]*m[9]*m[14]  + m[4]*m[10]*m[13] + m[8]*m[5]*m[14] - m[8]*m[6]*m[13] - m[12]*m[5]*m[10] + m[12]*m[6]*m[9];
    inv[1]  = -m[1]*m[10]*m[15] + m[1]*m[11]*m[14] + m[9]*m[2]*m[15] - m[9]*m[3]*m[14] - m[13]*m[2]*m[11] + m[13]*m[3]*m[10];
    inv[5]  =  m[0]*m[10]*m[15] - m[0]*m[11]*m[14] - m[8]*m[2]*m[15] + m[8]*m[3]*m[14] + m[12]*m[2]*m[11] - m[12]*m[3]*m[10];
    inv[9]  = -m[0]*m[9]*m[15]  + m[0]*m[11]*m[13] + m[8]*m[1]*m[15] - m[8]*m[3]*m[13] - m[12]*m[1]*m[11] + m[12]*m[3]*m[9];
    inv[13] =  m[0]*m[9]*m[14]  - m[0]*m[10]*m[13] - m[8]*m[1]*m[14] + m[8]*m[2]*m[13] + m[12]*m[1]*m[10] - m[12]*m[2]*m[9];
    inv[2]  =  m[1]*m[6]*m[15]  - m[1]*m[7]*m[14]  - m[5]*m[2]*m[15] + m[5]*m[3]*m[14] + m[13]*m[2]*m[7]  - m[13]*m[3]*m[6];
    inv[6]  = -m[0]*m[6]*m[15]  + m[0]*m[7]*m[14]  + m[4]*m[2]*m[15] - m[4]*m[3]*m[14] - m[12]*m[2]*m[7]  + m[12]*m[3]*m[6];
    inv[10] =  m[0]*m[5]*m[15]  - m[0]*m[7]*m[13]  - m[4]*m[1]*m[15] + m[4]*m[3]*m[13] + m[12]*m[1]*m[7]  - m[12]*m[3]*m[5];
    inv[14] = -m[0]*m[5]*m[14]  + m[0]*m[6]*m[13]  + m[4]*m[1]*m[14] - m[4]*m[2]*m[13] - m[12]*m[1]*m[6]  + m[12]*m[2]*m[5];
    inv[3]  = -m[1]*m[6]*m[11]  + m[1]*m[7]*m[10]  + m[5]*m[2]*m[11] - m[5]*m[3]*m[10] - m[9]*m[2]*m[7]   + m[9]*m[3]*m[6];
    inv[7]  =  m[0]*m[6]*m[11]  - m[0]*m[7]*m[10]  - m[4]*m[2]*m[11] + m[4]*m[3]*m[10] + m[8]*m[2]*m[7]   - m[8]*m[3]*m[6];
    inv[11] = -m[0]*m[5]*m[11]  + m[0]*m[7]*m[9]   + m[4]*m[1]*m[11] - m[4]*m[3]*m[9]  - m[8]*m[1]*m[7]   + m[8]*m[3]*m[5];
    inv[15] =  m[0]*m[5]*m[10]  - m[0]*m[6]*m[9]   - m[4]*m[1]*m[10] + m[4]*m[2]*m[9]  + m[8]*m[1]*m[6]   - m[8]*m[2]*m[5];
    float det = m[0]*inv[0] + m[1]*inv[4] + m[2]*inv[8] + m[3]*inv[12];
    det = 1.0f / det;
    #pragma unroll
    for (int i = 0; i < 16; ++i) inv[i] *= det;
}

// ---------------------------------------------------------------------------
// Kernel 1: per-gaussian projection (8 blocks x 256). Writes z-key + params.
__global__ __launch_bounds__(256) void preprocess_kernel(
    const float* __restrict__ means,  const float* __restrict__ quats,
    const float* __restrict__ scales, const float* __restrict__ opac_logits,
    const float* __restrict__ c2o,    const float* __restrict__ Kmat,
    float* __restrict__ zkey, float* __restrict__ evalp, float* __restrict__ bboxp)
{
    const int i = blockIdx.x * 256 + threadIdx.x;
    if (i >= NG) return;

    float inv[16];
    {
        float m[16];
        #pragma unroll
        for (int t = 0; t < 16; ++t) m[t] = c2o[t];
        invert4x4(m, inv);   // viewmat, row-major
    }
    const float fx = Kmat[0], fy = Kmat[4], cx = Kmat[2], cy = Kmat[5];

    float mx = means[i*3+0], my = means[i*3+1], mz = means[i*3+2];
    float X = inv[0]*mx + inv[1]*my + inv[2]*mz  + inv[3];
    float Y = inv[4]*mx + inv[5]*my + inv[6]*mz  + inv[7];
    float Z = inv[8]*mx + inv[9]*my + inv[10]*mz + inv[11];

    float qw = quats[i*4+0], qx = quats[i*4+1], qy = quats[i*4+2], qz = quats[i*4+3];
    float qn = rsqrtf(qw*qw + qx*qx + qy*qy + qz*qz);
    qw *= qn; qx *= qn; qy *= qn; qz *= qn;
    float R00 = 1.f - 2.f*(qy*qy + qz*qz), R01 = 2.f*(qx*qy - qw*qz), R02 = 2.f*(qx*qz + qw*qy);
    float R10 = 2.f*(qx*qy + qw*qz), R11 = 1.f - 2.f*(qx*qx + qz*qz), R12 = 2.f*(qy*qz - qw*qx);
    float R20 = 2.f*(qx*qz - qw*qy), R21 = 2.f*(qy*qz + qw*qx), R22 = 1.f - 2.f*(qx*qx + qy*qy);

    float s0 = expf(scales[i*3+0]), s1 = expf(scales[i*3+1]), s2 = expf(scales[i*3+2]);
    float M00 = R00*s0, M01 = R01*s1, M02 = R02*s2;
    float M10 = R10*s0, M11 = R11*s1, M12 = R12*s2;
    float M20 = R20*s0, M21 = R21*s1, M22 = R22*s2;

    float V[3][3];
    V[0][0] = M00*M00 + M01*M01 + M02*M02;
    V[0][1] = M00*M10 + M01*M11 + M02*M12;
    V[0][2] = M00*M20 + M01*M21 + M02*M22;
    V[1][1] = M10*M10 + M11*M11 + M12*M12;
    V[1][2] = M10*M20 + M11*M21 + M12*M22;
    V[2][2] = M20*M20 + M21*M21 + M22*M22;
    V[1][0] = V[0][1]; V[2][0] = V[0][2]; V[2][1] = V[1][2];

    float Rv[3][3] = {{inv[0],inv[1],inv[2]},{inv[4],inv[5],inv[6]},{inv[8],inv[9],inv[10]}};
    float Tm[3][3], C[3][3];
    #pragma unroll
    for (int r = 0; r < 3; ++r)
        #pragma unroll
        for (int c = 0; c < 3; ++c)
            Tm[r][c] = Rv[r][0]*V[0][c] + Rv[r][1]*V[1][c] + Rv[r][2]*V[2][c];
    #pragma unroll
    for (int r = 0; r < 3; ++r)
        #pragma unroll
        for (int c = 0; c < 3; ++c)
            C[r][c] = Tm[r][0]*Rv[c][0] + Tm[r][1]*Rv[c][1] + Tm[r][2]*Rv[c][2];

    float rz = 1.0f / Z;
    float j00 = fx*rz, j02 = -fx*X*rz*rz;
    float j11 = fy*rz, j12 = -fy*Y*rz*rz;

    float c00 = j00*j00*C[0][0] + 2.f*j00*j02*C[0][2] + j02*j02*C[2][2];
    float c01 = j00*j11*C[0][1] + j00*j12*C[0][2] + j02*j11*C[1][2] + j02*j12*C[2][2];
    float c11 = j11*j11*C[1][1] + 2.f*j11*j12*C[1][2] + j12*j12*C[2][2];

    float a = c00 + P_BLUR;
    float b = c01;
    float c = c11 + P_BLUR;
    float det = a*c - b*b;

    float pmx = fx*X*rz + cx;
    float pmy = fy*Y*rz + cy;

    float lam = 0.5f*(a + c) + sqrtf(fmaxf(0.25f*(a - c)*(a - c) + b*b, 1e-12f));
    float radius = 3.0f * sqrtf(lam);
    bool valid = (Z > P_NEAR) && (det > 0.0f) && (radius > 3.0f);

    float op = 1.0f / (1.0f + expf(-opac_logits[i]));

    float cA = 0.f, cB = 0.f, cC = 0.f, rx = -1e9f, ry = -1e9f;
    if (valid) {
        float rdet = 1.0f / det;
        cA = c * rdet; cB = -b * rdet; cC = a * rdet;
        // conservative extent: alpha >= A_MIN needs sigma <= ln(255*op);
        // min-over-dy sigma = dx^2/(2a) => |dx| <= sqrt(2*a*smax)
        float smax = logf(255.0f * op);
        if (smax > 0.f) {
            rx = sqrtf(2.f * a * smax) * 1.0001f + 1e-3f;
            ry = sqrtf(2.f * c * smax) * 1.0001f + 1e-3f;
        }
    } else {
        op = 0.f;
    }

    zkey[i] = Z;
    ((float4*)evalp)[i*2]   = make_float4(pmx, pmy, cA, cB);
    ((float4*)evalp)[i*2+1] = make_float4(cC, op, 0.f, 0.f);
    ((float4*)bboxp)[i]     = make_float4(pmx, pmy, rx, ry);
}

// ---------------------------------------------------------------------------
// Kernel 2a: partial rank counts. Grid = 8 i-blocks x 8 j-chunks = 64 blocks.
// Block (ib, jc): stage z[jc*256 .. +256) in LDS, each thread counts for its
// gaussian i how many j in the chunk sort before i (stable (z, idx) order).
// No atomics: partial[jc][i], summed by the next kernel.
__global__ __launch_bounds__(256) void rank_partial_kernel(
    const float* __restrict__ zkey, int* __restrict__ partial)
{
    __shared__ float zj[JCN];
    const int ib = blockIdx.x & 7;
    const int jc = blockIdx.x >> 3;
    const int tid = threadIdx.x;
    const int i = ib * 256 + tid;

    zj[tid] = zkey[jc * JCN + tid];
    __syncthreads();

    const float zi = zkey[i];
    const int jbase = jc * JCN;
    const float4* z4 = (const float4*)zj;
    int cnt = 0;
    #pragma unroll 8
    for (int c = 0; c < JCN/4; ++c) {
        float4 z = z4[c];
        int j = jbase + 4*c;
        cnt += (z.x < zi) || (z.x == zi && (j+0) < i);
        cnt += (z.y < zi) || (z.y == zi && (j+1) < i);
        cnt += (z.z < zi) || (z.z == zi && (j+2) < i);
        cnt += (z.w < zi) || (z.w == zi && (j+3) < i);
    }
    partial[jc * NG + i] = cnt;
}

// ---------------------------------------------------------------------------
// Kernel 2b: sum partials -> rank, scatter params to sorted slot.
// Original index stashed in evalps slot [8i+6] for colors lookup.
__global__ __launch_bounds__(256) void permute_kernel(
    const int* __restrict__ partial, const float* __restrict__ evalp,
    const float* __restrict__ bboxp, float* __restrict__ evalps,
    float* __restrict__ bboxs)
{
    const int i = blockIdx.x * 256 + threadIdx.x;
    if (i >= NG) return;
    int rank = 0;
    #pragma unroll
    for (int c = 0; c < JC; ++c) rank += partial[c * NG + i];

    float4 lo = ((const float4*)evalp)[i*2];
    float4 hi = ((const float4*)evalp)[i*2+1];
    hi.z = __int_as_float(i);
    ((float4*)evalps)[rank*2]   = lo;
    ((float4*)evalps)[rank*2+1] = hi;
    ((float4*)bboxs)[rank]      = ((const float4*)bboxp)[i];
}

// ---------------------------------------------------------------------------
// Kernel 3: render — round-3 verbatim (measured 44.8us, VGPR 80, no spill).
// 256 blocks (one 8x8 tile), 8 waves; wave s owns z-segment s; lane = pixel.
// Serial front-to-back compositing in registers; colors streamed as
// wave-uniform broadcast float4 loads; all-zero rows skipped via ballot;
// segment partials combined affinely in LDS.
__global__ __launch_bounds__(RB, 2) void render_kernel(
    const float* __restrict__ evalps, const float* __restrict__ bboxs,
    const float* __restrict__ colors, float* __restrict__ out)
{
    extern __shared__ float lds[];
    const int tid  = threadIdx.x;
    const int lane = tid & 63;
    const int seg  = tid >> 6;
    const int tile = blockIdx.x;
    const int tx = (tile & 15) * 8;
    const int ty = (tile >> 4) * 8;
    const float px = tx + (lane & 7) + 0.5f;
    const float py = ty + (lane >> 3) + 0.5f;
    const float cxt = tx + 4.0f, cyt = ty + 4.0f;

    // ---- cull this z-segment into an LDS list (z order preserved)
    int* list = (int*)(lds + L_LIST) + seg * SEGN;
    int cnt = 0;
    const float4* bb4 = (const float4*)bboxs;
    for (int c = 0; c < SEGN; c += 64) {
        int g = seg * SEGN + c + lane;           // sorted position
        float4 bb = bb4[g];
        bool sel = (fabsf(bb.x - cxt) <= bb.z + 3.5f) &&
                   (fabsf(bb.y - cyt) <= bb.w + 3.5f);
        unsigned long long m = __ballot(sel);
        if (sel) list[cnt + (int)__popcll(m & ((1ull << lane) - 1ull))] = g;
        cnt += (int)__popcll(m);
    }

    float acc[64];
    #pragma unroll
    for (int f = 0; f < 64; ++f) acc[f] = 0.f;
    float T = 1.0f;

    const float4* ep4 = (const float4*)evalps;
    const float4* cp4 = (const float4*)colors;

    if (cnt > 0) {
        int gi = list[0];
        float4 e0 = ep4[gi*2], e1 = ep4[gi*2+1];
        for (int r = 0; r < cnt; ++r) {
            int gin = (r + 1 < cnt) ? list[r + 1] : gi;
            float4 n0 = ep4[gin*2], n1 = ep4[gin*2+1];   // prefetch next params

            float dx = px - e0.x, dy = py - e0.y;
            float sig = 0.5f*(e0.z*dx*dx + e1.x*dy*dy) + e0.w*dx*dy;
            float al = fminf(e1.y * __expf(-sig), P_AMAX);
            al = (sig >= 0.f && al >= P_AMIN) ? al : 0.f;

            if (__ballot(al > 0.f)) {
                float wv = T * al;
                const float4* crow = cp4 + (size_t)(unsigned)__float_as_int(e1.z) * 16;
                #pragma unroll
                for (int q = 0; q < 16; ++q) {
                    float4 cv = crow[q];                  // wave-uniform broadcast
                    acc[4*q+0] = fmaf(wv, cv.x, acc[4*q+0]);
                    acc[4*q+1] = fmaf(wv, cv.y, acc[4*q+1]);
                    acc[4*q+2] = fmaf(wv, cv.z, acc[4*q+2]);
                    acc[4*q+3] = fmaf(wv, cv.w, acc[4*q+3]);
                }
                T *= (1.f - al);
                if (!__ballot(T >= 1e-6f)) break;   // whole wave dead -> done
            }
            e0 = n0; e1 = n1;
        }
    }

    // ---- stage per-segment (acc, T) to LDS
    {
        float* ab = lds + L_ACC + (size_t)(seg * 64 + lane) * ACC_STRIDE;
        #pragma unroll
        for (int q = 0; q < 32; ++q)
            *(float2*)(ab + 2*q) = make_float2(acc[2*q], acc[2*q+1]);
        lds[L_T + seg*64 + lane] = T;
    }
    __syncthreads();

    // ---- affine combine: out = a0 + T0*(a1 + T1*(...))
    {
        int p  = tid >> 3;
        int f0 = (tid & 7) * 8;
        float r[8];
        const float* ab = lds + L_ACC + (size_t)((SEG-1)*64 + p) * ACC_STRIDE + f0;
        #pragma unroll
        for (int j = 0; j < 4; ++j) {
            float2 u = *(const float2*)(ab + 2*j);
            r[2*j] = u.x; r[2*j+1] = u.y;
        }
        #pragma unroll
        for (int s = SEG - 2; s >= 0; --s) {
            float Ts = lds[L_T + s*64 + p];
            const float* as_ = lds + L_ACC + (size_t)(s*64 + p) * ACC_STRIDE + f0;
            #pragma unroll
            for (int j = 0; j < 4; ++j) {
                float2 u = *(const float2*)(as_ + 2*j);
                r[2*j]   = fmaf(Ts, r[2*j],   u.x);
                r[2*j+1] = fmaf(Ts, r[2*j+1], u.y);
            }
        }
        int pyg = ty + (p >> 3), pxg = tx + (p & 7);
        float* op_ = out + (size_t)(pyg * IW + pxg) * DF + f0;
        *(float4*)op_       = make_float4(r[0], r[1], r[2], r[3]);
        *(float4*)(op_ + 4) = make_float4(r[4], r[5], r[6], r[7]);
    }
}

// ---------------------------------------------------------------------------
extern "C" void kernel_launch(void* const* d_in, const int* in_sizes, int n_in,
                              void* d_out, int out_size, void* d_ws, size_t ws_size,
                              hipStream_t stream) {
    const float* means  = (const float*)d_in[0];
    const float* quats  = (const float*)d_in[1];
    const float* scales = (const float*)d_in[2];
    const float* opac   = (const float*)d_in[3];
    const float* colors = (const float*)d_in[4];
    const float* c2o    = (const float*)d_in[5];
    const float* Kmat   = (const float*)d_in[6];
    float* out = (float*)d_out;

    // ws (floats): zkey[NG] | evalp[8NG] | bboxp[4NG] | evalps[8NG] | bboxs[4NG]
    //            | partial[8NG ints]  = 264 KiB
    float* ws     = (float*)d_ws;
    float* zkey   = ws;
    float* evalp  = ws + NG;
    float* bboxp  = ws + NG*9;
    float* evalps = ws + NG*13;
    float* bboxs  = ws + NG*21;
    int*   partial= (int*)(ws + NG*25);

    (void)hipFuncSetAttribute((const void*)render_kernel,
                              hipFuncAttributeMaxDynamicSharedMemorySize,
                              L_TOTAL * 4);

    preprocess_kernel<<<NG/256, 256, 0, stream>>>(means, quats, scales, opac, c2o, Kmat,
                                                  zkey, evalp, bboxp);
    rank_partial_kernel<<<8 * JC, 256, 0, stream>>>(zkey, partial);
    permute_kernel<<<NG/256, 256, 0, stream>>>(partial, evalp, bboxp, evalps, bboxs);
    render_kernel<<<IH*IW/64, RB, L_TOTAL*4, stream>>>(evalps, bboxs, colors, out);
}

// Round 6
// 118.708 us; speedup vs baseline: 1.6831x; 1.0427x over previous
//
#include <hip/hip_runtime.h>

constexpr int NG  = 2048;   // gaussians
constexpr int DF  = 64;     // feature dim
constexpr int IW  = 128;
constexpr int IH  = 128;
constexpr int SEG = 8;            // waves per block (each takes an equal slice of the sorted list)
constexpr int RB  = SEG * 64;     // 512 threads
constexpr int CAP = 1024;         // per-tile culled-list capacity (analysis bound ~350 max)

#define P_NEAR 0.01f
#define P_BLUR 0.3f
#define P_AMIN (1.0f/255.0f)
#define P_AMAX 0.999f

// LDS layout (floats). ACC overlays PRM+KEYS (dead after composite; barrier in between).
constexpr int L_T    = 0;                    // SEG*64 = 512
constexpr int L_CNT  = 512;                  // 16 (int counter at [512])
constexpr int L_SIDX = 528;                  // CAP ints = 1024
constexpr int L_ACC  = L_SIDX + CAP;         // 1552 (ACC region, 8*64*66 = 33792 floats)
constexpr int L_PRM  = L_ACC;                // params: CAP*8 = 8192 floats (overlaid by ACC later)
constexpr int L_KEYS = L_PRM + CAP * 8;      // 9744: CAP u64 keys = 2048 floats (overlaid later)
constexpr int ACC_STRIDE = 66;               // 64 + 2 pad
constexpr int L_TOTAL = L_ACC + SEG * 64 * ACC_STRIDE;   // 35344 floats = 141,376 B

// ---------------------------------------------------------------------------
__device__ inline void invert4x4(const float* m, float* inv) {
    inv[0]  =  m[5]*m[10]*m[15] - m[5]*m[11]*m[14] - m[9]*m[6]*m[15] + m[9]*m[7]*m[14] + m[13]*m[6]*m[11] - m[13]*m[7]*m[10];
    inv[4]  = -m[4]*m[10]*m[15] + m[4]*m[11]*m[14] + m[8]*m[6]*m[15] - m[8]*m[7]*m[14] - m[12]*m[6]*m[11] + m[12]*m[7]*m[10];
    inv[8]  =  m[4]*m[9]*m[15]  - m[4]*m[11]*m[13] - m[8]*m[5]*m[15] + m[8]*m[7]*m[13] + m[12]*m[5]*m[11] - m[12]*m[7]*m[9];
    inv[12] = -m[4]*m[9]*m[14]  + m[4]*m[10]*m[13] + m[8]*m[5]*m[14] - m[8]*m[6]*m[13] - m[12]*m[5]*m[10] + m[12]*m[6]*m[9];
    inv[1]  = -m[1]*m[10]*m[15] + m[1]*m[11]*m[14] + m[9]*m[2]*m[15] - m[9]*m[3]*m[14] - m[13]*m[2]*m[11] + m[13]*m[3]*m[10];
    inv[5]  =  m[0]*m[10]*m[15] - m[0]*m[11]*m[14] - m[8]*m[2]*m[15] + m[8]*m[3]*m[14] + m[12]*m[2]*m[11] - m[12]*m[3]*m[10];
    inv[9]  = -m[0]*m[9]*m[15]  + m[0]*m[11]*m[13] + m[8]*m[1]*m[15] - m[8]*m[3]*m[13] - m[12]*m[1]*m[11] + m[12]*m[3]*m[9];
    inv[13] =  m[0]*m[9]*m[14]  - m[0]*m[10]*m[13] - m[8]*m[1]*m[14] + m[8]*m[2]*m[13] + m[12]*m[1]*m[10] - m[12]*m[2]*m[9];
    inv[2]  =  m[1]*m[6]*m[15]  - m[1]*m[7]*m[14]  - m[5]*m[2]*m[15] + m[5]*m[3]*m[14] + m[13]*m[2]*m[7]  - m[13]*m[3]*m[6];
    inv[6]  = -m[0]*m[6]*m[15]  + m[0]*m[7]*m[14]  + m[4]*m[2]*m[15] - m[4]*m[3]*m[14] - m[12]*m[2]*m[7]  + m[12]*m[3]*m[6];
    inv[10] =  m[0]*m[5]*m[15]  - m[0]*m[7]*m[13]  - m[4]*m[1]*m[15] + m[4]*m[3]*m[13] + m[12]*m[1]*m[7]  - m[12]*m[3]*m[5];
    inv[14] = -m[0]*m[5]*m[14]  + m[0]*m[6]*m[13]  + m[4]*m[1]*m[14] - m[4]*m[2]*m[13] - m[12]*m[1]*m[6]  + m[12]*m[2]*m[5];
    inv[3]  = -m[1]*m[6]*m[11]  + m[1]*m[7]*m[10]  + m[5]*m[2]*m[11] - m[5]*m[3]*m[10] - m[9]*m[2]*m[7]   + m[9]*m[3]*m[6];
    inv[7]  =  m[0]*m[6]*m[11]  - m[0]*m[7]*m[10]  - m[4]*m[2]*m[11] + m[4]*m[3]*m[10] + m[8]*m[2]*m[7]   - m[8]*m[3]*m[6];
    inv[11] = -m[0]*m[5]*m[11]  + m[0]*m[7]*m[9]   + m[4]*m[1]*m[11] - m[4]*m[3]*m[9]  - m[8]*m[1]*m[7]   + m[8]*m[3]*m[5];
    inv[15] =  m[0]*m[5]*m[10]  - m[0]*m[6]*m[9]   - m[4]*m[1]*m[10] + m[4]*m[2]*m[9]  + m[8]*m[1]*m[6]   - m[8]*m[2]*m[5];
    float det = m[0]*inv[0] + m[1]*inv[4] + m[2]*inv[8] + m[3]*inv[12];
    det = 1.0f / det;
    #pragma unroll
    for (int i = 0; i < 16; ++i) inv[i] *= det;
}

// ---------------------------------------------------------------------------
// ONE kernel: per-tile fused preprocess + cull + local stable sort + composite.
// 256 blocks (one 8x8 tile each), 512 threads. No cross-block communication:
// each block redundantly projects all 2048 gaussians (~1us on its own CU),
// keeps only those overlapping its tile (z order irrelevant at this point),
// rank-sorts the survivors by packed (z_bits, idx) u64 key — exactly
// jnp.argsort's stable order restricted to the subset — then composites
// front-to-back with register-prefetched color rows.
__global__ __launch_bounds__(RB) void fused_render_kernel(
    const float* __restrict__ means,  const float* __restrict__ quats,
    const float* __restrict__ scales, const float* __restrict__ opac_logits,
    const float* __restrict__ colors, const float* __restrict__ c2o,
    const float* __restrict__ Kmat,   float* __restrict__ out)
{
    extern __shared__ float lds[];
    int*                cnt  = (int*)(lds + L_CNT);
    int*                sidx = (int*)(lds + L_SIDX);
    unsigned long long* keys = (unsigned long long*)(lds + L_KEYS);
    float4*             prm4 = (float4*)(lds + L_PRM);

    const int tid  = threadIdx.x;
    const int lane = tid & 63;
    const int seg  = tid >> 6;
    const int tile = blockIdx.x;
    const int tx = (tile & 15) * 8;
    const int ty = (tile >> 4) * 8;
    const float px = tx + (lane & 7) + 0.5f;
    const float py = ty + (lane >> 3) + 0.5f;
    const float cxt = tx + 4.0f, cyt = ty + 4.0f;

    if (tid == 0) *cnt = 0;
    __syncthreads();

    // ---- phase 1: preprocess all gaussians, append tile-overlapping to LDS
    {
        float inv[16];
        {
            float m[16];
            #pragma unroll
            for (int t = 0; t < 16; ++t) m[t] = c2o[t];
            invert4x4(m, inv);   // viewmat, row-major
        }
        const float fx = Kmat[0], fy = Kmat[4], cx = Kmat[2], cy = Kmat[5];

        for (int c = 0; c < NG / RB; ++c) {
            const int g = c * RB + tid;
            float mx = means[g*3+0], my = means[g*3+1], mz = means[g*3+2];
            float X = inv[0]*mx + inv[1]*my + inv[2]*mz  + inv[3];
            float Y = inv[4]*mx + inv[5]*my + inv[6]*mz  + inv[7];
            float Z = inv[8]*mx + inv[9]*my + inv[10]*mz + inv[11];

            float qw = quats[g*4+0], qx = quats[g*4+1], qy = quats[g*4+2], qz = quats[g*4+3];
            float qn = rsqrtf(qw*qw + qx*qx + qy*qy + qz*qz);
            qw *= qn; qx *= qn; qy *= qn; qz *= qn;
            float R00 = 1.f - 2.f*(qy*qy + qz*qz), R01 = 2.f*(qx*qy - qw*qz), R02 = 2.f*(qx*qz + qw*qy);
            float R10 = 2.f*(qx*qy + qw*qz), R11 = 1.f - 2.f*(qx*qx + qz*qz), R12 = 2.f*(qy*qz - qw*qx);
            float R20 = 2.f*(qx*qz - qw*qy), R21 = 2.f*(qy*qz + qw*qx), R22 = 1.f - 2.f*(qx*qx + qy*qy);

            float s0 = expf(scales[g*3+0]), s1 = expf(scales[g*3+1]), s2 = expf(scales[g*3+2]);
            float M00 = R00*s0, M01 = R01*s1, M02 = R02*s2;
            float M10 = R10*s0, M11 = R11*s1, M12 = R12*s2;
            float M20 = R20*s0, M21 = R21*s1, M22 = R22*s2;

            float V00 = M00*M00 + M01*M01 + M02*M02;
            float V01 = M00*M10 + M01*M11 + M02*M12;
            float V02 = M00*M20 + M01*M21 + M02*M22;
            float V11 = M10*M10 + M11*M11 + M12*M12;
            float V12 = M10*M20 + M11*M21 + M12*M22;
            float V22 = M20*M20 + M21*M21 + M22*M22;

            // cov_c = Rv V Rv^T
            float Rv[3][3] = {{inv[0],inv[1],inv[2]},{inv[4],inv[5],inv[6]},{inv[8],inv[9],inv[10]}};
            float Vm[3][3] = {{V00,V01,V02},{V01,V11,V12},{V02,V12,V22}};
            float Tm[3][3], C[3][3];
            #pragma unroll
            for (int r = 0; r < 3; ++r)
                #pragma unroll
                for (int cc = 0; cc < 3; ++cc)
                    Tm[r][cc] = Rv[r][0]*Vm[0][cc] + Rv[r][1]*Vm[1][cc] + Rv[r][2]*Vm[2][cc];
            #pragma unroll
            for (int r = 0; r < 3; ++r)
                #pragma unroll
                for (int cc = 0; cc < 3; ++cc)
                    C[r][cc] = Tm[r][0]*Rv[cc][0] + Tm[r][1]*Rv[cc][1] + Tm[r][2]*Rv[cc][2];

            float rz = 1.0f / Z;
            float j00 = fx*rz, j02 = -fx*X*rz*rz;
            float j11 = fy*rz, j12 = -fy*Y*rz*rz;

            float c00 = j00*j00*C[0][0] + 2.f*j00*j02*C[0][2] + j02*j02*C[2][2];
            float c01 = j00*j11*C[0][1] + j00*j12*C[0][2] + j02*j11*C[1][2] + j02*j12*C[2][2];
            float c11 = j11*j11*C[1][1] + 2.f*j11*j12*C[1][2] + j12*j12*C[2][2];

            float a = c00 + P_BLUR;
            float b = c01;
            float cc_ = c11 + P_BLUR;
            float det = a*cc_ - b*b;

            float pmx = fx*X*rz + cx;
            float pmy = fy*Y*rz + cy;

            float lam = 0.5f*(a + cc_) + sqrtf(fmaxf(0.25f*(a - cc_)*(a - cc_) + b*b, 1e-12f));
            float radius = 3.0f * sqrtf(lam);
            bool valid = (Z > P_NEAR) && (det > 0.0f) && (radius > 3.0f);

            float op = 1.0f / (1.0f + expf(-opac_logits[g]));

            bool sel = false;
            float cA = 0.f, cB = 0.f, cC2 = 0.f;
            if (valid) {
                float rdet = 1.0f / det;
                cA = cc_ * rdet; cB = -b * rdet; cC2 = a * rdet;
                // exact conservative extent: alpha >= A_MIN needs sigma <= ln(255*op);
                // min-over-dy sigma = dx^2/(2a) => |dx| <= sqrt(2*a*smax)
                float smax = logf(255.0f * op);
                if (smax > 0.f) {
                    float rx = sqrtf(2.f * a   * smax) * 1.0001f + 1e-3f;
                    float ry = sqrtf(2.f * cc_ * smax) * 1.0001f + 1e-3f;
                    sel = (fabsf(pmx - cxt) <= rx + 3.5f) && (fabsf(pmy - cyt) <= ry + 3.5f);
                }
            }

            unsigned long long m = __ballot(sel);
            int wbase = 0;
            if (lane == 0 && m) wbase = atomicAdd(cnt, (int)__popcll(m));
            wbase = __shfl(wbase, 0);
            if (sel) {
                int pos = wbase + (int)__popcll(m & ((1ull << lane) - 1ull));
                if (pos < CAP) {
                    prm4[pos*2]   = make_float4(pmx, pmy, cA, cB);
                    prm4[pos*2+1] = make_float4(cC2, op, __int_as_float(g), 0.f);
                    keys[pos] = ((unsigned long long)__float_as_uint(Z) << 32) | (unsigned)g;
                }
            }
        }
    }
    __syncthreads();
    int L = *cnt;
    if (L > CAP) L = CAP;

    // ---- phase 2: stable rank-sort of the culled list via (z,idx) u64 keys
    {
        int padL = (L + 1) & ~1;
        if (tid < padL - L) keys[L + tid] = ~0ull;   // pad keys rank last
        __syncthreads();
        const ulonglong2* k2 = (const ulonglong2*)keys;
        for (int k = tid; k < L; k += RB) {
            unsigned long long kk = keys[k];
            int rank = 0;
            #pragma unroll 2
            for (int c = 0; c < padL / 2; ++c) {
                ulonglong2 q = k2[c];                // wave-uniform broadcast
                rank += (q.x < kk) + (q.y < kk);
            }
            sidx[rank] = k;
        }
    }
    __syncthreads();

    // ---- phase 3: composite. wave `seg` takes sorted rows [seg*L/8, (seg+1)*L/8)
    float acc[64];
    #pragma unroll
    for (int f = 0; f < 64; ++f) acc[f] = 0.f;
    float T = 1.0f;

    {
        const int r0 = (seg * L) >> 3;
        const int r1 = ((seg + 1) * L) >> 3;
        const float4* cp4 = (const float4*)colors;
        if (r1 > r0) {
            int k = sidx[r0];
            float4 e0 = prm4[k*2], e1 = prm4[k*2+1];
            for (int r = r0; r < r1; ++r) {
                int kn = (r + 1 < r1) ? sidx[r + 1] : k;
                float4 f0 = prm4[kn*2], f1 = prm4[kn*2+1];   // prefetch next params

                // hoist the 16 color loads ahead of the alpha math (reg prefetch)
                const float4* crow = cp4 + (size_t)(unsigned)__float_as_int(e1.z) * 16;
                float4 cbuf[16];
                #pragma unroll
                for (int q = 0; q < 16; ++q) cbuf[q] = crow[q];

                float dx = px - e0.x, dy = py - e0.y;
                float sig = 0.5f*(e0.z*dx*dx + e1.x*dy*dy) + e0.w*dx*dy;
                float al = fminf(e1.y * __expf(-sig), P_AMAX);
                al = (sig >= 0.f && al >= P_AMIN) ? al : 0.f;

                if (__ballot(al > 0.f)) {
                    float wv = T * al;
                    #pragma unroll
                    for (int q = 0; q < 16; ++q) {
                        acc[4*q+0] = fmaf(wv, cbuf[q].x, acc[4*q+0]);
                        acc[4*q+1] = fmaf(wv, cbuf[q].y, acc[4*q+1]);
                        acc[4*q+2] = fmaf(wv, cbuf[q].z, acc[4*q+2]);
                        acc[4*q+3] = fmaf(wv, cbuf[q].w, acc[4*q+3]);
                    }
                    T *= (1.f - al);
                    if (!__ballot(T >= 1e-6f)) break;   // whole wave saturated
                }
                e0 = f0; e1 = f1; k = kn;
            }
        }
    }

    // ---- phase 4: stage per-segment (acc, T); ACC overlays PRM/KEYS (dead now)
    __syncthreads();   // everyone done reading prm/sidx... sidx is outside ACC; prm inside
    {
        float* ab = lds + L_ACC + (size_t)(seg * 64 + lane) * ACC_STRIDE;
        #pragma unroll
        for (int q = 0; q < 32; ++q)
            *(float2*)(ab + 2*q) = make_float2(acc[2*q], acc[2*q+1]);
        lds[L_T + seg*64 + lane] = T;
    }
    __syncthreads();

    // ---- affine combine: out = a0 + T0*(a1 + T1*(...))
    {
        int p  = tid >> 3;
        int f0 = (tid & 7) * 8;
        float r[8];
        const float* ab = lds + L_ACC + (size_t)((SEG-1)*64 + p) * ACC_STRIDE + f0;
        #pragma unroll
        for (int j = 0; j < 4; ++j) {
            float2 u = *(const float2*)(ab + 2*j);
            r[2*j] = u.x; r[2*j+1] = u.y;
        }
        #pragma unroll
        for (int s = SEG - 2; s >= 0; --s) {
            float Ts = lds[L_T + s*64 + p];
            const float* as_ = lds + L_ACC + (size_t)(s*64 + p) * ACC_STRIDE + f0;
            #pragma unroll
            for (int j = 0; j < 4; ++j) {
                float2 u = *(const float2*)(as_ + 2*j);
                r[2*j]   = fmaf(Ts, r[2*j],   u.x);
                r[2*j+1] = fmaf(Ts, r[2*j+1], u.y);
            }
        }
        int pyg = ty + (p >> 3), pxg = tx + (p & 7);
        float* op_ = out + (size_t)(pyg * IW + pxg) * DF + f0;
        *(float4*)op_       = make_float4(r[0], r[1], r[2], r[3]);
        *(float4*)(op_ + 4) = make_float4(r[4], r[5], r[6], r[7]);
    }
}

// ---------------------------------------------------------------------------
extern "C" void kernel_launch(void* const* d_in, const int* in_sizes, int n_in,
                              void* d_out, int out_size, void* d_ws, size_t ws_size,
                              hipStream_t stream) {
    const float* means  = (const float*)d_in[0];
    const float* quats  = (const float*)d_in[1];
    const float* scales = (const float*)d_in[2];
    const float* opac   = (const float*)d_in[3];
    const float* colors = (const float*)d_in[4];
    const float* c2o    = (const float*)d_in[5];
    const float* Kmat   = (const float*)d_in[6];
    float* out = (float*)d_out;
    (void)d_ws; (void)ws_size;

    (void)hipFuncSetAttribute((const void*)fused_render_kernel,
                              hipFuncAttributeMaxDynamicSharedMemorySize,
                              L_TOTAL * 4);

    fused_render_kernel<<<IH*IW/64, RB, L_TOTAL*4, stream>>>(
        means, quats, scales, opac, colors, c2o, Kmat, out);
}